// Round 14
// baseline (106.523 us; speedup 1.0000x reference)
//
#include <hip/hip_runtime.h>
#include <hip/hip_bf16.h>
#include <stdint.h>

// Problem: B=4, S=1024, D=1024, H=16, hd=64; fp32 in/out, bf16 MFMA inside.
typedef float f32x4 __attribute__((ext_vector_type(4)));
typedef __bf16 bf16x8 __attribute__((ext_vector_type(8)));

#define MFMA(a, b, c) __builtin_amdgcn_mfma_f32_16x16x32_bf16((a), (b), (c), 0, 0, 0)

__device__ __forceinline__ bf16x8 ld8(const void* p) { return *(const bf16x8*)p; }

__device__ __forceinline__ bf16x8 ld8f(const float* p) {
    float4 a = *(const float4*)p;
    float4 b = *(const float4*)(p + 4);
    bf16x8 r;
    r[0] = (__bf16)a.x; r[1] = (__bf16)a.y; r[2] = (__bf16)a.z; r[3] = (__bf16)a.w;
    r[4] = (__bf16)b.x; r[5] = (__bf16)b.y; r[6] = (__bf16)b.z; r[7] = (__bf16)b.w;
    return r;
}

__device__ __forceinline__ void gload16(const void* g, void* l) {
    __builtin_amdgcn_global_load_lds(
        (const __attribute__((address_space(1))) void*)g,
        (__attribute__((address_space(3))) void*)l, 16, 0, 0);
}

// Swizzle for 128-byte LDS rows: XOR row bits into the 16B-slot bits (G4 / T2).
#define SW(row, cb) ((((row) * 128) + (cb)) ^ (((row) & 7) << 4))
// V-transpose swizzle: also mix row>>3 so writes at row-stride-8 spread banks.
#define SWV(row, cb) (((row) * 128) + ((cb) ^ (((((row) & 7) ^ (((row) >> 3) & 7))) << 4)))

// log2-domain softmax scale: 0.125 * log2(e)  (folded into Q at GEMM epilogue)
#define SCALE2 0.18033688011112042f

// ---------------- fused fp32 -> bf16 convert: X then W (contiguous out) -----
__global__ void convert2_kernel(const float* __restrict__ X,
                                const float* __restrict__ W,
                                __bf16* __restrict__ out) {
    const size_t i = (size_t)(blockIdx.x * 256 + threadIdx.x) * 8;
    const size_t NX = (size_t)4096 * 1024;
    if (i < NX) *(bf16x8*)(out + i) = ld8f(X + i);
    else        *(bf16x8*)(out + i) = ld8f(W + (i - NX));
}

// ---------------- RoPE cos/sin table: [1024 pos][32 j] float2(cos,sin) -------
__global__ void rope_table_kernel(float2* __restrict__ rope) {
    const int idx = blockIdx.x * 256 + threadIdx.x;  // 32768 entries
    const int t = idx >> 5, j = idx & 31;
    const float invf = __expf(-(float)j * 0.28782313662425575f);  // ln(10000)/32
    const float ang = (float)t * invf;
    float s, c;
    sincosf(ang, &s, &c);
    rope[idx] = make_float2(c, s);
}

// ---------------- fast QKV GEMM: 2-phase double-buffered (T3 minimal) --------
// STAGE(next) issued BEFORE compute(cur); single __syncthreads per k-step
// performs the recipe's vmcnt(0)+barrier. gload_lds prefetch = 0 VGPR cost.
// LDS read path bank-conflict-free (rule #21: inverse-swizzled global source
// + SW-swizzled ds_read). Epilogue: bias + RoPE; q scaled by SCALE2.
__global__ __launch_bounds__(256, 2) void qkv_rope_fast(
    const __bf16* __restrict__ Xb,    // [4096][1024]
    const __bf16* __restrict__ Wb,    // [3072][1024]
    const float* __restrict__ bias,   // [3072]
    const float2* __restrict__ rope,  // [1024][32]
    __bf16* __restrict__ QKV)         // [4096][3072]
{
    __shared__ __align__(16) __bf16 Asm[2][128 * 64];
    __shared__ __align__(16) __bf16 Bsm[2][128 * 64];
    const int tid = threadIdx.x;
    const int w = tid >> 6, lane = tid & 63;
    const int fr = lane & 15, fq = lane >> 4;
    const int wr = w >> 1, wn = w & 1;
    const int bn = blockIdx.x, bm = blockIdx.y;

    const int srow = w * 32 + (lane >> 3);
    // Inverse-swizzled source column: chunk (lane&7)^(row&7); row&7 == lane>>3.
    const int scol = (((lane & 7) ^ (lane >> 3)) & 7) * 8;
    const __bf16* ga = Xb + (size_t)(bm * 128 + srow) * 1024 + scol;
    const __bf16* gb = Wb + (size_t)(bn * 128 + srow) * 1024 + scol;

#define STAGE(bb, kt)                                                          \
    do {                                                                       \
        _Pragma("unroll") for (int i = 0; i < 4; ++i) {                        \
            gload16(ga + (size_t)(i * 8) * 1024 + (kt) * 64,                   \
                    &Asm[bb][w * 2048 + i * 512]);                             \
            gload16(gb + (size_t)(i * 8) * 1024 + (kt) * 64,                   \
                    &Bsm[bb][w * 2048 + i * 512]);                             \
        }                                                                      \
    } while (0)

    const f32x4 fzero = {0.f, 0.f, 0.f, 0.f};
    f32x4 acc[4][4];
#pragma unroll
    for (int i = 0; i < 4; ++i)
#pragma unroll
        for (int j = 0; j < 4; ++j) acc[i][j] = fzero;

    STAGE(0, 0);
    __syncthreads();  // tile 0 staged (vmcnt drained by syncthreads semantics)

    int cur = 0;
    for (int kt = 0; kt < 16; ++kt) {
        // issue next tile's loads FIRST -> latency hides under compute below
        if (kt + 1 < 16) STAGE(cur ^ 1, kt + 1);

        const uint8_t* Ab = (const uint8_t*)Asm[cur];
        const uint8_t* Bb = (const uint8_t*)Bsm[cur];
        bf16x8 af[4][2], bg[4][2];
#pragma unroll
        for (int mi = 0; mi < 4; ++mi)
#pragma unroll
            for (int kk = 0; kk < 2; ++kk)
                af[mi][kk] = ld8(&Ab[SW(wr * 64 + mi * 16 + fr, kk * 64 + fq * 16)]);
#pragma unroll
        for (int ni = 0; ni < 4; ++ni)
#pragma unroll
            for (int kk = 0; kk < 2; ++kk)
                bg[ni][kk] = ld8(&Bb[SW(wn * 64 + ni * 16 + fr, kk * 64 + fq * 16)]);
#pragma unroll
        for (int kk = 0; kk < 2; ++kk)
#pragma unroll
            for (int mi = 0; mi < 4; ++mi)
#pragma unroll
                for (int ni = 0; ni < 4; ++ni)
                    acc[mi][ni] = MFMA(af[mi][kk], bg[ni][kk], acc[mi][ni]);

        __syncthreads();  // = vmcnt(0)+barrier: next buffer staged, reads done
        cur ^= 1;
    }
#undef STAGE

    const int n0 = bn * 128 + wn * 64;
    const int region = n0 >> 10;  // 0=q, 1=k, 2=v
    float bia[4];
#pragma unroll
    for (int ni = 0; ni < 4; ++ni) bia[ni] = bias[n0 + ni * 16 + fr];
#pragma unroll
    for (int mi = 0; mi < 4; ++mi) {
#pragma unroll
        for (int jr = 0; jr < 4; ++jr) {
            const int rg = bm * 128 + wr * 64 + mi * 16 + fq * 4 + jr;
            const int spos = rg & 1023;
            float v0 = acc[mi][0][jr] + bia[0];
            float v1 = acc[mi][1][jr] + bia[1];
            float v2 = acc[mi][2][jr] + bia[2];
            float v3 = acc[mi][3][jr] + bia[3];
            if (region < 2) {
                const float2 cs0 = rope[spos * 32 + fr];
                const float2 cs1 = rope[spos * 32 + 16 + fr];
                const float t0 = v0, t1 = v1;
                v0 = t0 * cs0.x - v2 * cs0.y;
                v2 = v2 * cs0.x + t0 * cs0.y;
                v1 = t1 * cs1.x - v3 * cs1.y;
                v3 = v3 * cs1.x + t1 * cs1.y;
                if (region == 0) {  // fold softmax scale into q
                    v0 *= SCALE2; v1 *= SCALE2; v2 *= SCALE2; v3 *= SCALE2;
                }
            }
            __bf16* op = QKV + (size_t)rg * 3072 + n0 + fr;
            op[0]  = (__bf16)v0;
            op[16] = (__bf16)v1;
            op[32] = (__bf16)v2;
            op[48] = (__bf16)v3;
        }
    }
}

// ---------------- fallback QKV GEMM: fp32 inputs, register staging -----------
__global__ __launch_bounds__(256, 2) void qkv_rope_slow(
    const float* __restrict__ X, const float* __restrict__ W,
    const float* __restrict__ bias, const float2* __restrict__ rope,
    __bf16* __restrict__ QKV)
{
    __shared__ __align__(16) __bf16 Asm[128 * 64];
    __shared__ __align__(16) __bf16 Bsm[128 * 64];
    const int tid = threadIdx.x;
    const int w = tid >> 6, lane = tid & 63;
    const int fr = lane & 15, fq = lane >> 4;
    const int wr = w >> 1, wn = w & 1;
    const int bn = blockIdx.x, bm = blockIdx.y;
    const int srow = w * 32 + (lane >> 3);
    const int scol = (lane & 7) * 8;
    const float* ga = X + (size_t)(bm * 128 + srow) * 1024 + scol;
    const float* gb = W + (size_t)(bn * 128 + srow) * 1024 + scol;
    const int ldst = w * 2048 + lane * 8;

    const f32x4 fzero = {0.f, 0.f, 0.f, 0.f};
    f32x4 acc[4][4];
#pragma unroll
    for (int i = 0; i < 4; ++i)
#pragma unroll
        for (int j = 0; j < 4; ++j) acc[i][j] = fzero;

    for (int kt = 0; kt < 16; ++kt) {
        bf16x8 av[4], bv[4];
#pragma unroll
        for (int i = 0; i < 4; ++i) {
            av[i] = ld8f(ga + (size_t)(i * 8) * 1024 + kt * 64);
            bv[i] = ld8f(gb + (size_t)(i * 8) * 1024 + kt * 64);
        }
        __syncthreads();
#pragma unroll
        for (int i = 0; i < 4; ++i) {
            *(bf16x8*)&Asm[ldst + i * 512] = av[i];
            *(bf16x8*)&Bsm[ldst + i * 512] = bv[i];
        }
        __syncthreads();
        bf16x8 af[4][2], bg[4][2];
#pragma unroll
        for (int mi = 0; mi < 4; ++mi)
#pragma unroll
            for (int kk = 0; kk < 2; ++kk)
                af[mi][kk] = ld8(&Asm[(wr * 64 + mi * 16 + fr) * 64 + kk * 32 + fq * 8]);
#pragma unroll
        for (int ni = 0; ni < 4; ++ni)
#pragma unroll
            for (int kk = 0; kk < 2; ++kk)
                bg[ni][kk] = ld8(&Bsm[(wn * 64 + ni * 16 + fr) * 64 + kk * 32 + fq * 8]);
#pragma unroll
        for (int kk = 0; kk < 2; ++kk)
#pragma unroll
            for (int mi = 0; mi < 4; ++mi)
#pragma unroll
                for (int ni = 0; ni < 4; ++ni)
                    acc[mi][ni] = MFMA(af[mi][kk], bg[ni][kk], acc[mi][ni]);
    }

    const int n0 = bn * 128 + wn * 64;
    const int region = n0 >> 10;
    float bia[4];
#pragma unroll
    for (int ni = 0; ni < 4; ++ni) bia[ni] = bias[n0 + ni * 16 + fr];
#pragma unroll
    for (int mi = 0; mi < 4; ++mi) {
#pragma unroll
        for (int jr = 0; jr < 4; ++jr) {
            const int rg = bm * 128 + wr * 64 + mi * 16 + fq * 4 + jr;
            const int spos = rg & 1023;
            float v0 = acc[mi][0][jr] + bia[0];
            float v1 = acc[mi][1][jr] + bia[1];
            float v2 = acc[mi][2][jr] + bia[2];
            float v3 = acc[mi][3][jr] + bia[3];
            if (region < 2) {
                const float2 cs0 = rope[spos * 32 + fr];
                const float2 cs1 = rope[spos * 32 + 16 + fr];
                const float t0 = v0, t1 = v1;
                v0 = t0 * cs0.x - v2 * cs0.y;
                v2 = v2 * cs0.x + t0 * cs0.y;
                v1 = t1 * cs1.x - v3 * cs1.y;
                v3 = v3 * cs1.x + t1 * cs1.y;
                if (region == 0) {
                    v0 *= SCALE2; v1 *= SCALE2; v2 *= SCALE2; v3 *= SCALE2;
                }
            }
            __bf16* op = QKV + (size_t)rg * 3072 + n0 + fr;
            op[0]  = (__bf16)v0;
            op[16] = (__bf16)v1;
            op[32] = (__bf16)v2;
            op[48] = (__bf16)v3;
        }
    }
}

// ---------------- Flash attention (causal) -----------------------------------
// Unchanged (round 12): pair {jp,15-jp}, KVBLK=64, dbuf LDS, fixed-reference
// softmax (p = exp2(s) directly; scores bounded), l reduced in epilogue.
__global__ __launch_bounds__(256, 2) void attn_kernel(
    const __bf16* __restrict__ QKV,  // [4096][3072]
    float* __restrict__ Out)         // [4][1024][1024] fp32
{
    __shared__ __align__(16) uint8_t smem[40960];
    const int tid = threadIdx.x;
    const int w = tid >> 6, lane = tid & 63;
    const int fr = lane & 15, fq = lane >> 4;
    const int b = blockIdx.x >> 4, h = blockIdx.x & 15;
    const int jp = blockIdx.y;            // 0..7
    const int qtA = jp, qtB = 15 - jp;    // paired q-tiles
    const int q0A = qtA * 64, q0B = qtB * 64;
    const __bf16* base = QKV + (size_t)b * 1024 * 3072 + h * 64;

    bf16x8 qfA[2], qfB[2];
#pragma unroll
    for (int kk = 0; kk < 2; ++kk) {
        qfA[kk] = ld8(base + (size_t)(q0A + w * 16 + fr) * 3072 + kk * 32 + fq * 8);
        qfB[kk] = ld8(base + (size_t)(q0B + w * 16 + fr) * 3072 + kk * 32 + fq * 8);
    }

    const f32x4 fzero = {0.f, 0.f, 0.f, 0.f};
    f32x4 oA[4], oB[4];
    float lA[4], lB[4];
#pragma unroll
    for (int jr = 0; jr < 4; ++jr) { lA[jr] = 0.f; lB[jr] = 0.f; }
#pragma unroll
    for (int fn = 0; fn < 4; ++fn) { oA[fn] = fzero; oB[fn] = fzero; }

    const int skey = tid >> 3;       // 0..31
    const int scol = (tid & 7) * 8;  // 0..56
    const int nkt = qtB + 1;         // 16 - jp
    const int pb = 32768 + w * 2048;

    // prologue: stage tile 0 into buffer 0
    {
        const size_t g0 = (size_t)skey * 3072;
        const size_t g1 = (size_t)(32 + skey) * 3072;
        bf16x8 kxa = ld8(base + g0 + 1024 + scol);
        bf16x8 kxb = ld8(base + g1 + 1024 + scol);
        bf16x8 vxa = ld8(base + g0 + 2048 + scol);
        bf16x8 vxb = ld8(base + g1 + 2048 + scol);
        *(bf16x8*)&smem[SW(skey, scol * 2)] = kxa;
        *(bf16x8*)&smem[SW(32 + skey, scol * 2)] = kxb;
#pragma unroll
        for (int jj = 0; jj < 8; ++jj) {
            *(__bf16*)&smem[8192 + SWV(scol + jj, skey * 2)] = vxa[jj];
            *(__bf16*)&smem[8192 + SWV(scol + jj, (32 + skey) * 2)] = vxb[jj];
        }
    }
    __syncthreads();

#define PROCESS(QF, O, L, Q0)                                                  \
    do {                                                                       \
        f32x4 sv[4];                                                           \
        _Pragma("unroll") for (int ni = 0; ni < 4; ++ni) sv[ni] = fzero;       \
        _Pragma("unroll") for (int kk = 0; kk < 2; ++kk) {                     \
            bf16x8 kf[4];                                                      \
            _Pragma("unroll") for (int ni = 0; ni < 4; ++ni)                   \
                kf[ni] = ld8(&smem[cb + SW(ni * 16 + fr, (kk * 32 + fq * 8) * 2)]); \
            _Pragma("unroll") for (int ni = 0; ni < 4; ++ni)                   \
                sv[ni] = MFMA(QF[kk], kf[ni], sv[ni]);                         \
        }                                                                      \
        if ((k0 + 63) > ((Q0) + w * 16)) {                                     \
            _Pragma("unroll") for (int ni = 0; ni < 4; ++ni)                   \
                _Pragma("unroll") for (int jr = 0; jr < 4; ++jr) {             \
                    const int rg = (Q0) + w * 16 + fq * 4 + jr;                \
                    const int kg = k0 + ni * 16 + fr;                          \
                    if (kg > rg) sv[ni][jr] = -1.0e30f;                        \
                }                                                              \
        }                                                                      \
        _Pragma("unroll") for (int jr = 0; jr < 4; ++jr) {                     \
            float ts = 0.f;                                                    \
            _Pragma("unroll") for (int ni = 0; ni < 4; ++ni) {                 \
                const float p = exp2f(sv[ni][jr]);                             \
                sv[ni][jr] = p;                                                \
                ts += p;                                                       \
            }                                                                  \
            L[jr] += ts;                                                       \
        }                                                                      \
        _Pragma("unroll") for (int ni = 0; ni < 4; ++ni)                       \
            _Pragma("unroll") for (int jr = 0; jr < 4; ++jr)                   \
                *(__bf16*)&smem[pb + SW(fq * 4 + jr, (ni * 16 + fr) * 2)] =    \
                    (__bf16)sv[ni][jr];                                        \
        _Pragma("unroll") for (int ks = 0; ks < 2; ++ks) {                     \
            bf16x8 pf = ld8(&smem[pb + SW(fr, (ks * 32 + fq * 8) * 2)]);       \
            bf16x8 vf[4];                                                      \
            _Pragma("unroll") for (int fn = 0; fn < 4; ++fn)                   \
                vf[fn] = ld8(&smem[cb + 8192 + SWV(fn * 16 + fr, (ks * 32 + fq * 8) * 2)]); \
            _Pragma("unroll") for (int fn = 0; fn < 4; ++fn)                   \
                O[fn] = MFMA(pf, vf[fn], O[fn]);                               \
        }                                                                      \
    } while (0)

    for (int kt = 0; kt < nkt; ++kt) {
        const int k0 = kt * 64;
        const int cb = (kt & 1) << 14;   // current buffer byte base
        const int nb = cb ^ 16384;       // next buffer byte base

        bf16x8 kxa, kxb, vxa, vxb;
        const bool pre = (kt + 1 < nkt);
        if (pre) {
            const size_t g0 = (size_t)(k0 + 64 + skey) * 3072;
            const size_t g1 = (size_t)(k0 + 96 + skey) * 3072;
            kxa = ld8(base + g0 + 1024 + scol);
            kxb = ld8(base + g1 + 1024 + scol);
            vxa = ld8(base + g0 + 2048 + scol);
            vxb = ld8(base + g1 + 2048 + scol);
        }

        if (kt <= qtA) PROCESS(qfA, oA, lA, q0A);  // block-uniform branch
        PROCESS(qfB, oB, lB, q0B);

        if (pre) {
            *(bf16x8*)&smem[nb + SW(skey, scol * 2)] = kxa;
            *(bf16x8*)&smem[nb + SW(32 + skey, scol * 2)] = kxb;
#pragma unroll
            for (int jj = 0; jj < 8; ++jj) {
                *(__bf16*)&smem[nb + 8192 + SWV(scol + jj, skey * 2)] = vxa[jj];
                *(__bf16*)&smem[nb + 8192 + SWV(scol + jj, (32 + skey) * 2)] = vxb[jj];
            }
        }
        __syncthreads();  // next buffer staged; all reads of cb done
    }
#undef PROCESS

#pragma unroll
    for (int jr = 0; jr < 4; ++jr) {
        float la = lA[jr], lb = lB[jr];
#pragma unroll
        for (int off = 1; off < 16; off <<= 1) {
            la += __shfl_xor(la, off, 64);
            lb += __shfl_xor(lb, off, 64);
        }
        const float invA = 1.0f / fmaxf(la, 1.0e-20f);
        const float invB = 1.0f / fmaxf(lb, 1.0e-20f);
        const int rgA = q0A + w * 16 + fq * 4 + jr;
        const int rgB = q0B + w * 16 + fq * 4 + jr;
        float* opA = Out + (size_t)(b * 1024 + rgA) * 1024 + h * 64 + fr;
        float* opB = Out + (size_t)(b * 1024 + rgB) * 1024 + h * 64 + fr;
#pragma unroll
        for (int fn = 0; fn < 4; ++fn) {
            opA[fn * 16] = oA[fn][jr] * invA;
            opB[fn * 16] = oB[fn][jr] * invB;
        }
    }
}

extern "C" void kernel_launch(void* const* d_in, const int* in_sizes, int n_in,
                              void* d_out, int out_size, void* d_ws, size_t ws_size,
                              hipStream_t stream) {
    const float* X = (const float*)d_in[0];     // [4,1024,1024]
    const float* W = (const float*)d_in[1];     // [3072,1024]
    const float* bias = (const float*)d_in[2];  // [3072]
    float* out = (float*)d_out;

    const size_t ROPE = 262144;
    const size_t XB = ROPE + (size_t)4096 * 1024 * 2;
    const size_t WB = XB + (size_t)3072 * 1024 * 2;
    const size_t need_fast = WB + (size_t)3072 * 1024 * 2 + (size_t)4096 * 3072 * 2;

    float2* rope = (float2*)d_ws;
    rope_table_kernel<<<128, 256, 0, stream>>>(rope);

    if (ws_size >= need_fast) {
        __bf16* Xb = (__bf16*)((char*)d_ws + ROPE);
        __bf16* Wb = (__bf16*)((char*)d_ws + XB);
        __bf16* qkv = (__bf16*)((char*)d_ws + WB + (size_t)3072 * 1024 * 2);
        convert2_kernel<<<3584, 256, 0, stream>>>(X, W, Xb);  // Xb||Wb contiguous
        qkv_rope_fast<<<dim3(24, 32), 256, 0, stream>>>(Xb, Wb, bias, rope, qkv);
        attn_kernel<<<dim3(64, 8), 256, 0, stream>>>(qkv, out);
    } else {
        __bf16* qkv = (__bf16*)((char*)d_ws + ROPE);
        qkv_rope_slow<<<dim3(24, 32), 256, 0, stream>>>(X, W, bias, rope, qkv);
        attn_kernel<<<dim3(64, 8), 256, 0, stream>>>(qkv, out);
    }
}

// Round 15
// 72.107 us; speedup vs baseline: 1.4773x; 1.4773x over previous
//
#include <hip/hip_runtime.h>
#include <hip/hip_bf16.h>
#include <stdint.h>

// Problem: B=4, S=1024, D=1024, H=16, hd=64; fp32 in/out, bf16 MFMA inside.
typedef float f32x4 __attribute__((ext_vector_type(4)));
typedef __bf16 bf16x8 __attribute__((ext_vector_type(8)));

#define MFMA(a, b, c) __builtin_amdgcn_mfma_f32_16x16x32_bf16((a), (b), (c), 0, 0, 0)

__device__ __forceinline__ bf16x8 ld8(const void* p) { return *(const bf16x8*)p; }

__device__ __forceinline__ bf16x8 ld8f(const float* p) {
    float4 a = *(const float4*)p;
    float4 b = *(const float4*)(p + 4);
    bf16x8 r;
    r[0] = (__bf16)a.x; r[1] = (__bf16)a.y; r[2] = (__bf16)a.z; r[3] = (__bf16)a.w;
    r[4] = (__bf16)b.x; r[5] = (__bf16)b.y; r[6] = (__bf16)b.z; r[7] = (__bf16)b.w;
    return r;
}

// raw v_exp_f32 (2^x); input bounded (masked -> -1e30 -> 0), skips ocml fixups
__device__ __forceinline__ float fexp2(float x) {
    float r;
    asm("v_exp_f32 %0, %1" : "=v"(r) : "v"(x));
    return r;
}

__device__ __forceinline__ void gload16(const void* g, void* l) {
    __builtin_amdgcn_global_load_lds(
        (const __attribute__((address_space(1))) void*)g,
        (__attribute__((address_space(3))) void*)l, 16, 0, 0);
}

// Swizzle for 128-byte LDS rows: XOR row bits into the 16B-slot bits (G4 / T2).
#define SW(row, cb) ((((row) * 128) + (cb)) ^ (((row) & 7) << 4))
// V-transpose swizzle: also mix row>>3 so writes at row-stride-8 spread banks.
#define SWV(row, cb) (((row) * 128) + ((cb) ^ (((((row) & 7) ^ (((row) >> 3) & 7))) << 4)))

// log2-domain softmax scale: 0.125 * log2(e)  (folded into Q at GEMM epilogue)
#define SCALE2 0.18033688011112042f

// -------- fused fp32->bf16 convert (X then W) + RoPE table, one dispatch ----
__global__ void convert2_kernel(const float* __restrict__ X,
                                const float* __restrict__ W,
                                __bf16* __restrict__ out,
                                float2* __restrict__ rope) {
    const int bid = blockIdx.x;
    if (bid < 3584) {
        const size_t i = (size_t)(bid * 256 + threadIdx.x) * 8;
        const size_t NX = (size_t)4096 * 1024;
        if (i < NX) *(bf16x8*)(out + i) = ld8f(X + i);
        else        *(bf16x8*)(out + i) = ld8f(W + (i - NX));
    } else {
        const int idx = (bid - 3584) * 256 + threadIdx.x;  // 32768 entries
        const int t = idx >> 5, j = idx & 31;
        const float invf = __expf(-(float)j * 0.28782313662425575f);
        const float ang = (float)t * invf;
        float s, c;
        sincosf(ang, &s, &c);
        rope[idx] = make_float2(c, s);
    }
}

// ---------------- RoPE table standalone (fallback path only) ----------------
__global__ void rope_table_kernel(float2* __restrict__ rope) {
    const int idx = blockIdx.x * 256 + threadIdx.x;
    const int t = idx >> 5, j = idx & 31;
    const float invf = __expf(-(float)j * 0.28782313662425575f);
    const float ang = (float)t * invf;
    float s, c;
    sincosf(ang, &s, &c);
    rope[idx] = make_float2(c, s);
}

// ---------------- fast QKV GEMM (round-13 proven version) -------------------
// Single-buffer 2-barrier; conflict-free (rule #21: inverse-swizzled global
// source + SW-swizzled ds_read). Epilogue: bias + RoPE; q scaled by SCALE2.
__global__ __launch_bounds__(256, 2) void qkv_rope_fast(
    const __bf16* __restrict__ Xb,    // [4096][1024]
    const __bf16* __restrict__ Wb,    // [3072][1024]
    const float* __restrict__ bias,   // [3072]
    const float2* __restrict__ rope,  // [1024][32]
    __bf16* __restrict__ QKV)         // [4096][3072]
{
    __shared__ __align__(16) __bf16 Asm[128 * 64];
    __shared__ __align__(16) __bf16 Bsm[128 * 64];
    const int tid = threadIdx.x;
    const int w = tid >> 6, lane = tid & 63;
    const int fr = lane & 15, fq = lane >> 4;
    const int wr = w >> 1, wn = w & 1;
    const int bn = blockIdx.x, bm = blockIdx.y;

    const int srow = w * 32 + (lane >> 3);
    const int scol = (((lane & 7) ^ (lane >> 3)) & 7) * 8;  // inverse swizzle
    const __bf16* ga = Xb + (size_t)(bm * 128 + srow) * 1024 + scol;
    const __bf16* gb = Wb + (size_t)(bn * 128 + srow) * 1024 + scol;
    __bf16* lA = &Asm[w * 2048];
    __bf16* lB = &Bsm[w * 2048];
    const uint8_t* Ab = (const uint8_t*)Asm;
    const uint8_t* Bb = (const uint8_t*)Bsm;

    const f32x4 fzero = {0.f, 0.f, 0.f, 0.f};
    f32x4 acc[4][4];
#pragma unroll
    for (int i = 0; i < 4; ++i)
#pragma unroll
        for (int j = 0; j < 4; ++j) acc[i][j] = fzero;

    for (int kt = 0; kt < 16; ++kt) {
        __syncthreads();
#pragma unroll
        for (int i = 0; i < 4; ++i) {
            gload16(ga + (size_t)(i * 8) * 1024 + kt * 64, lA + i * 512);
            gload16(gb + (size_t)(i * 8) * 1024 + kt * 64, lB + i * 512);
        }
        __syncthreads();

        bf16x8 af[4][2], bg[4][2];
#pragma unroll
        for (int mi = 0; mi < 4; ++mi)
#pragma unroll
            for (int kk = 0; kk < 2; ++kk)
                af[mi][kk] = ld8(&Ab[SW(wr * 64 + mi * 16 + fr, kk * 64 + fq * 16)]);
#pragma unroll
        for (int ni = 0; ni < 4; ++ni)
#pragma unroll
            for (int kk = 0; kk < 2; ++kk)
                bg[ni][kk] = ld8(&Bb[SW(wn * 64 + ni * 16 + fr, kk * 64 + fq * 16)]);
#pragma unroll
        for (int kk = 0; kk < 2; ++kk)
#pragma unroll
            for (int mi = 0; mi < 4; ++mi)
#pragma unroll
                for (int ni = 0; ni < 4; ++ni)
                    acc[mi][ni] = MFMA(af[mi][kk], bg[ni][kk], acc[mi][ni]);
    }

    const int n0 = bn * 128 + wn * 64;
    const int region = n0 >> 10;  // 0=q, 1=k, 2=v
    float bia[4];
#pragma unroll
    for (int ni = 0; ni < 4; ++ni) bia[ni] = bias[n0 + ni * 16 + fr];
#pragma unroll
    for (int mi = 0; mi < 4; ++mi) {
#pragma unroll
        for (int jr = 0; jr < 4; ++jr) {
            const int rg = bm * 128 + wr * 64 + mi * 16 + fq * 4 + jr;
            const int spos = rg & 1023;
            float v0 = acc[mi][0][jr] + bia[0];
            float v1 = acc[mi][1][jr] + bia[1];
            float v2 = acc[mi][2][jr] + bia[2];
            float v3 = acc[mi][3][jr] + bia[3];
            if (region < 2) {
                const float2 cs0 = rope[spos * 32 + fr];
                const float2 cs1 = rope[spos * 32 + 16 + fr];
                const float t0 = v0, t1 = v1;
                v0 = t0 * cs0.x - v2 * cs0.y;
                v2 = v2 * cs0.x + t0 * cs0.y;
                v1 = t1 * cs1.x - v3 * cs1.y;
                v3 = v3 * cs1.x + t1 * cs1.y;
                if (region == 0) {  // fold softmax scale into q
                    v0 *= SCALE2; v1 *= SCALE2; v2 *= SCALE2; v3 *= SCALE2;
                }
            }
            __bf16* op = QKV + (size_t)rg * 3072 + n0 + fr;
            op[0]  = (__bf16)v0;
            op[16] = (__bf16)v1;
            op[32] = (__bf16)v2;
            op[48] = (__bf16)v3;
        }
    }
}

// ---------------- fallback QKV GEMM: fp32 inputs, register staging -----------
__global__ __launch_bounds__(256, 2) void qkv_rope_slow(
    const float* __restrict__ X, const float* __restrict__ W,
    const float* __restrict__ bias, const float2* __restrict__ rope,
    __bf16* __restrict__ QKV)
{
    __shared__ __align__(16) __bf16 Asm[128 * 64];
    __shared__ __align__(16) __bf16 Bsm[128 * 64];
    const int tid = threadIdx.x;
    const int w = tid >> 6, lane = tid & 63;
    const int fr = lane & 15, fq = lane >> 4;
    const int wr = w >> 1, wn = w & 1;
    const int bn = blockIdx.x, bm = blockIdx.y;
    const int srow = w * 32 + (lane >> 3);
    const int scol = (lane & 7) * 8;
    const float* ga = X + (size_t)(bm * 128 + srow) * 1024 + scol;
    const float* gb = W + (size_t)(bn * 128 + srow) * 1024 + scol;
    const int ldst = w * 2048 + lane * 8;

    const f32x4 fzero = {0.f, 0.f, 0.f, 0.f};
    f32x4 acc[4][4];
#pragma unroll
    for (int i = 0; i < 4; ++i)
#pragma unroll
        for (int j = 0; j < 4; ++j) acc[i][j] = fzero;

    for (int kt = 0; kt < 16; ++kt) {
        bf16x8 av[4], bv[4];
#pragma unroll
        for (int i = 0; i < 4; ++i) {
            av[i] = ld8f(ga + (size_t)(i * 8) * 1024 + kt * 64);
            bv[i] = ld8f(gb + (size_t)(i * 8) * 1024 + kt * 64);
        }
        __syncthreads();
#pragma unroll
        for (int i = 0; i < 4; ++i) {
            *(bf16x8*)&Asm[ldst + i * 512] = av[i];
            *(bf16x8*)&Bsm[ldst + i * 512] = bv[i];
        }
        __syncthreads();
        bf16x8 af[4][2], bg[4][2];
#pragma unroll
        for (int mi = 0; mi < 4; ++mi)
#pragma unroll
            for (int kk = 0; kk < 2; ++kk)
                af[mi][kk] = ld8(&Asm[(wr * 64 + mi * 16 + fr) * 64 + kk * 32 + fq * 8]);
#pragma unroll
        for (int ni = 0; ni < 4; ++ni)
#pragma unroll
            for (int kk = 0; kk < 2; ++kk)
                bg[ni][kk] = ld8(&Bsm[(wn * 64 + ni * 16 + fr) * 64 + kk * 32 + fq * 8]);
#pragma unroll
        for (int kk = 0; kk < 2; ++kk)
#pragma unroll
            for (int mi = 0; mi < 4; ++mi)
#pragma unroll
                for (int ni = 0; ni < 4; ++ni)
                    acc[mi][ni] = MFMA(af[mi][kk], bg[ni][kk], acc[mi][ni]);
    }

    const int n0 = bn * 128 + wn * 64;
    const int region = n0 >> 10;
    float bia[4];
#pragma unroll
    for (int ni = 0; ni < 4; ++ni) bia[ni] = bias[n0 + ni * 16 + fr];
#pragma unroll
    for (int mi = 0; mi < 4; ++mi) {
#pragma unroll
        for (int jr = 0; jr < 4; ++jr) {
            const int rg = bm * 128 + wr * 64 + mi * 16 + fq * 4 + jr;
            const int spos = rg & 1023;
            float v0 = acc[mi][0][jr] + bia[0];
            float v1 = acc[mi][1][jr] + bia[1];
            float v2 = acc[mi][2][jr] + bia[2];
            float v3 = acc[mi][3][jr] + bia[3];
            if (region < 2) {
                const float2 cs0 = rope[spos * 32 + fr];
                const float2 cs1 = rope[spos * 32 + 16 + fr];
                const float t0 = v0, t1 = v1;
                v0 = t0 * cs0.x - v2 * cs0.y;
                v2 = v2 * cs0.x + t0 * cs0.y;
                v1 = t1 * cs1.x - v3 * cs1.y;
                v3 = v3 * cs1.x + t1 * cs1.y;
                if (region == 0) {
                    v0 *= SCALE2; v1 *= SCALE2; v2 *= SCALE2; v3 *= SCALE2;
                }
            }
            __bf16* op = QKV + (size_t)rg * 3072 + n0 + fr;
            op[0]  = (__bf16)v0;
            op[16] = (__bf16)v1;
            op[32] = (__bf16)v2;
            op[48] = (__bf16)v3;
        }
    }
}

// ---------------- Flash attention (causal) -----------------------------------
// Pair {jp,15-jp}, KVBLK=64, dbuf LDS, fixed-reference softmax (p=exp2(s)).
// MERGED dual-PROCESS: when both q-tiles active, kf and vf fragments are read
// ONCE and feed both MFMA sets (-12% avg LDS ops).
__global__ __launch_bounds__(256, 2) void attn_kernel(
    const __bf16* __restrict__ QKV,  // [4096][3072]
    float* __restrict__ Out)         // [4][1024][1024] fp32
{
    __shared__ __align__(16) uint8_t smem[49152];
    // buf at {0,16384}: K [64][64] SW | +8192: Vt [64][64] SWV
    // [32768 + w*4096): P_A at +0, P_B at +2048 ([16 rows][64 keys] SW each)
    const int tid = threadIdx.x;
    const int w = tid >> 6, lane = tid & 63;
    const int fr = lane & 15, fq = lane >> 4;
    const int b = blockIdx.x >> 4, h = blockIdx.x & 15;
    const int jp = blockIdx.y;            // 0..7
    const int qtA = jp, qtB = 15 - jp;    // paired q-tiles
    const int q0A = qtA * 64, q0B = qtB * 64;
    const __bf16* base = QKV + (size_t)b * 1024 * 3072 + h * 64;

    bf16x8 qfA[2], qfB[2];
#pragma unroll
    for (int kk = 0; kk < 2; ++kk) {
        qfA[kk] = ld8(base + (size_t)(q0A + w * 16 + fr) * 3072 + kk * 32 + fq * 8);
        qfB[kk] = ld8(base + (size_t)(q0B + w * 16 + fr) * 3072 + kk * 32 + fq * 8);
    }

    const f32x4 fzero = {0.f, 0.f, 0.f, 0.f};
    f32x4 oA[4], oB[4];
    float lA[4], lB[4];
#pragma unroll
    for (int jr = 0; jr < 4; ++jr) { lA[jr] = 0.f; lB[jr] = 0.f; }
#pragma unroll
    for (int fn = 0; fn < 4; ++fn) { oA[fn] = fzero; oB[fn] = fzero; }

    const int skey = tid >> 3;       // 0..31
    const int scol = (tid & 7) * 8;  // 0..56
    const int nkt = qtB + 1;         // 16 - jp
    const int pbA = 32768 + w * 4096;
    const int pbB = pbA + 2048;

    // prologue: stage tile 0 into buffer 0
    {
        const size_t g0 = (size_t)skey * 3072;
        const size_t g1 = (size_t)(32 + skey) * 3072;
        bf16x8 kxa = ld8(base + g0 + 1024 + scol);
        bf16x8 kxb = ld8(base + g1 + 1024 + scol);
        bf16x8 vxa = ld8(base + g0 + 2048 + scol);
        bf16x8 vxb = ld8(base + g1 + 2048 + scol);
        *(bf16x8*)&smem[SW(skey, scol * 2)] = kxa;
        *(bf16x8*)&smem[SW(32 + skey, scol * 2)] = kxb;
#pragma unroll
        for (int jj = 0; jj < 8; ++jj) {
            *(__bf16*)&smem[8192 + SWV(scol + jj, skey * 2)] = vxa[jj];
            *(__bf16*)&smem[8192 + SWV(scol + jj, (32 + skey) * 2)] = vxb[jj];
        }
    }
    __syncthreads();

// mask + exp + P-write for one q-tile's scores (sv in-place -> p)
#define MASKEXP_WRITE(SV, Q0, PB)                                              \
    do {                                                                       \
        if ((k0 + 63) > ((Q0) + w * 16)) {                                     \
            _Pragma("unroll") for (int ni = 0; ni < 4; ++ni)                   \
                _Pragma("unroll") for (int jr = 0; jr < 4; ++jr) {             \
                    const int rg = (Q0) + w * 16 + fq * 4 + jr;                \
                    const int kg = k0 + ni * 16 + fr;                          \
                    if (kg > rg) SV[ni][jr] = -1.0e30f;                        \
                }                                                              \
        }                                                                      \
        _Pragma("unroll") for (int jr = 0; jr < 4; ++jr) {                     \
            float ts = 0.f;                                                    \
            _Pragma("unroll") for (int ni = 0; ni < 4; ++ni) {                 \
                const float p = fexp2(SV[ni][jr]);                             \
                SV[ni][jr] = p;                                                \
                ts += p;                                                       \
            }                                                                  \
            (PB == pbA ? lA : lB)[jr] += ts;                                   \
        }                                                                      \
        _Pragma("unroll") for (int ni = 0; ni < 4; ++ni)                       \
            _Pragma("unroll") for (int jr = 0; jr < 4; ++jr)                   \
                *(__bf16*)&smem[(PB) + SW(fq * 4 + jr, (ni * 16 + fr) * 2)] =  \
                    (__bf16)SV[ni][jr];                                        \
    } while (0)

    for (int kt = 0; kt < nkt; ++kt) {
        const int k0 = kt * 64;
        const int cb = (kt & 1) << 14;   // current buffer byte base
        const int nb = cb ^ 16384;       // next buffer byte base
        const bool dual = (kt <= qtA);   // block-uniform

        // prefetch next tile into registers (latency hides under compute)
        bf16x8 kxa, kxb, vxa, vxb;
        const bool pre = (kt + 1 < nkt);
        if (pre) {
            const size_t g0 = (size_t)(k0 + 64 + skey) * 3072;
            const size_t g1 = (size_t)(k0 + 96 + skey) * 3072;
            kxa = ld8(base + g0 + 1024 + scol);
            kxb = ld8(base + g1 + 1024 + scol);
            vxa = ld8(base + g0 + 2048 + scol);
            vxb = ld8(base + g1 + 2048 + scol);
        }

        // QK^T for B (and A if dual) sharing the kf fragment reads
        f32x4 svA[4], svB[4];
#pragma unroll
        for (int ni = 0; ni < 4; ++ni) { svA[ni] = fzero; svB[ni] = fzero; }
#pragma unroll
        for (int kk = 0; kk < 2; ++kk) {
            bf16x8 kf[4];
#pragma unroll
            for (int ni = 0; ni < 4; ++ni)
                kf[ni] = ld8(&smem[cb + SW(ni * 16 + fr, (kk * 32 + fq * 8) * 2)]);
#pragma unroll
            for (int ni = 0; ni < 4; ++ni)
                svB[ni] = MFMA(qfB[kk], kf[ni], svB[ni]);
            if (dual) {
#pragma unroll
                for (int ni = 0; ni < 4; ++ni)
                    svA[ni] = MFMA(qfA[kk], kf[ni], svA[ni]);
            }
        }

        MASKEXP_WRITE(svB, q0B, pbB);
        if (dual) MASKEXP_WRITE(svA, q0A, pbA);
        // no barrier: P wave-private; same-wave ds order via lgkmcnt

        // PV for B (and A) sharing the vf fragment reads
#pragma unroll
        for (int ks = 0; ks < 2; ++ks) {
            bf16x8 vf[4];
#pragma unroll
            for (int fn = 0; fn < 4; ++fn)
                vf[fn] = ld8(&smem[cb + 8192 + SWV(fn * 16 + fr, (ks * 32 + fq * 8) * 2)]);
            bf16x8 pfB = ld8(&smem[pbB + SW(fr, (ks * 32 + fq * 8) * 2)]);
#pragma unroll
            for (int fn = 0; fn < 4; ++fn)
                oB[fn] = MFMA(pfB, vf[fn], oB[fn]);
            if (dual) {
                bf16x8 pfA = ld8(&smem[pbA + SW(fr, (ks * 32 + fq * 8) * 2)]);
#pragma unroll
                for (int fn = 0; fn < 4; ++fn)
                    oA[fn] = MFMA(pfA, vf[fn], oA[fn]);
            }
        }

        // stage next tile into the other buffer (no read/write overlap)
        if (pre) {
            *(bf16x8*)&smem[nb + SW(skey, scol * 2)] = kxa;
            *(bf16x8*)&smem[nb + SW(32 + skey, scol * 2)] = kxb;
#pragma unroll
            for (int jj = 0; jj < 8; ++jj) {
                *(__bf16*)&smem[nb + 8192 + SWV(scol + jj, skey * 2)] = vxa[jj];
                *(__bf16*)&smem[nb + 8192 + SWV(scol + jj, (32 + skey) * 2)] = vxb[jj];
            }
        }
        __syncthreads();  // next buffer staged; all reads of cb done
    }
#undef MASKEXP_WRITE

    // epilogue: cross-lane l reduction (l is lane-partial over fr), store fp32
#pragma unroll
    for (int jr = 0; jr < 4; ++jr) {
        float la = lA[jr], lb = lB[jr];
#pragma unroll
        for (int off = 1; off < 16; off <<= 1) {
            la += __shfl_xor(la, off, 64);
            lb += __shfl_xor(lb, off, 64);
        }
        const float invA = 1.0f / fmaxf(la, 1.0e-20f);
        const float invB = 1.0f / fmaxf(lb, 1.0e-20f);
        const int rgA = q0A + w * 16 + fq * 4 + jr;
        const int rgB = q0B + w * 16 + fq * 4 + jr;
        float* opA = Out + (size_t)(b * 1024 + rgA) * 1024 + h * 64 + fr;
        float* opB = Out + (size_t)(b * 1024 + rgB) * 1024 + h * 64 + fr;
#pragma unroll
        for (int fn = 0; fn < 4; ++fn) {
            opA[fn * 16] = oA[fn][jr] * invA;
            opB[fn * 16] = oB[fn][jr] * invB;
        }
    }
}

extern "C" void kernel_launch(void* const* d_in, const int* in_sizes, int n_in,
                              void* d_out, int out_size, void* d_ws, size_t ws_size,
                              hipStream_t stream) {
    const float* X = (const float*)d_in[0];     // [4,1024,1024]
    const float* W = (const float*)d_in[1];     // [3072,1024]
    const float* bias = (const float*)d_in[2];  // [3072]
    float* out = (float*)d_out;

    const size_t ROPE = 262144;
    const size_t XB = ROPE + (size_t)4096 * 1024 * 2;
    const size_t WB = XB + (size_t)3072 * 1024 * 2;
    const size_t need_fast = WB + (size_t)3072 * 1024 * 2 + (size_t)4096 * 3072 * 2;

    float2* rope = (float2*)d_ws;

    if (ws_size >= need_fast) {
        __bf16* Xb = (__bf16*)((char*)d_ws + ROPE);
        __bf16* Wb = (__bf16*)((char*)d_ws + XB);
        __bf16* qkv = (__bf16*)((char*)d_ws + WB + (size_t)3072 * 1024 * 2);
        convert2_kernel<<<3712, 256, 0, stream>>>(X, W, Xb, rope);  // + rope
        qkv_rope_fast<<<dim3(24, 32), 256, 0, stream>>>(Xb, Wb, bias, rope, qkv);
        attn_kernel<<<dim3(64, 8), 256, 0, stream>>>(qkv, out);
    } else {
        __bf16* qkv = (__bf16*)((char*)d_ws + ROPE);
        rope_table_kernel<<<128, 256, 0, stream>>>(rope);
        qkv_rope_slow<<<dim3(24, 32), 256, 0, stream>>>(X, W, bias, rope, qkv);
        attn_kernel<<<dim3(64, 8), 256, 0, stream>>>(qkv, out);
    }
}